// Round 3
// baseline (12391.176 us; speedup 1.0000x reference)
//
#include <hip/hip_runtime.h>

#define HB 64      // batch
#define HT 1024    // time
#define HI 256     // input dim
#define HH 512     // hidden dim

typedef short short8 __attribute__((ext_vector_type(8)));
typedef float f32x4 __attribute__((ext_vector_type(4)));
typedef int   i32x4 __attribute__((ext_vector_type(4)));   // asm-friendly 16B

__device__ __forceinline__ unsigned short f2bf(float f) {
    unsigned u = __float_as_uint(f);
    u += 0x7FFF + ((u >> 16) & 1);          // round-to-nearest-even
    return (unsigned short)(u >> 16);
}
__device__ __forceinline__ float bf2f(unsigned short s) {
    return __uint_as_float(((unsigned)s) << 16);
}
__device__ __forceinline__ float fsigmoid(float x) {
    return __builtin_amdgcn_rcpf(1.0f + __expf(-x));
}
__device__ __forceinline__ float ftanh(float x) {
    return 1.0f - 2.0f * __builtin_amdgcn_rcpf(__expf(2.0f * x) + 1.0f);
}

// 16B coherence-point store: {8B data, 4B tag, 4B zero} in ONE transaction.
__device__ __forceinline__ void st_pair16(void* p, i32x4 v) {
    asm volatile("global_store_dwordx4 %0, %1, off sc0 sc1"
                 :: "v"(p), "v"(v) : "memory");
}

// ---------------------------------------------------------------------------
// Tag-validated h pull: 16 fragments (= 32 tagged 16B pairs) per lane.
// Each pair was written by ONE producer lane as a single 16B store, so
// (data, tag) are transactionally consistent. Pull = poll: retry until all
// 32 tags of this wave's region equal `expect`. No flags, no drain, no
// barrier — each wave self-serves.
// Layout per (slot, mt): kt(16) x lane(64) x pair(2) x 16B; kt stride 2048B,
// lane stride 32B.
// ---------------------------------------------------------------------------
__device__ __forceinline__ void pull16(const char* base0, int expect, short8* af) {
    for (;;) {
        i32x4 v[32];
        const char* b = base0;
        #pragma unroll
        for (int bi = 0; bi < 8; ++bi) {   // 2 kt per bi
            asm volatile("global_load_dwordx4 %0, %1, off sc0 sc1"
                         : "=v"(v[bi * 4 + 0]) : "v"(b));
            asm volatile("global_load_dwordx4 %0, %1, off offset:16 sc0 sc1"
                         : "=v"(v[bi * 4 + 1]) : "v"(b));
            asm volatile("global_load_dwordx4 %0, %1, off offset:2048 sc0 sc1"
                         : "=v"(v[bi * 4 + 2]) : "v"(b));
            asm volatile("global_load_dwordx4 %0, %1, off offset:2064 sc0 sc1"
                         : "=v"(v[bi * 4 + 3]) : "v"(b));
            b += 4096;
        }
        asm volatile("s_waitcnt vmcnt(0)" ::: "memory");
        __builtin_amdgcn_sched_barrier(0);   // keep tag checks after the wait
        int ok = 1;
        #pragma unroll
        for (int i = 0; i < 32; ++i)
            ok &= (v[i][2] == expect) & (v[i][3] == 0);
        if (__ballot(ok != 0) == ~0ull) {
            #pragma unroll
            for (int kt = 0; kt < 16; ++kt) {
                union { int i4[4]; short8 s; } u;
                u.i4[0] = v[2 * kt][0];     u.i4[1] = v[2 * kt][1];
                u.i4[2] = v[2 * kt + 1][0]; u.i4[3] = v[2 * kt + 1][1];
                af[kt] = u.s;
            }
            return;
        }
        __builtin_amdgcn_s_sleep(2);
    }
}

// ---------------------------------------------------------------------------
// Pack weights to bf16 in MFMA B-fragment-linear layout (proven round 1).
// ---------------------------------------------------------------------------
__global__ void pack_weights(const float* __restrict__ Wih0, const float* __restrict__ Whh0,
                             const float* __restrict__ bih0, const float* __restrict__ bhh0,
                             const float* __restrict__ Wih1, const float* __restrict__ Whh1,
                             const float* __restrict__ bih1, const float* __restrict__ bhh1,
                             unsigned short* __restrict__ wp0,
                             unsigned short* __restrict__ wp1,
                             float* __restrict__ bs) {
    int idx = blockIdx.x * 256 + threadIdx.x;
    int stride = gridDim.x * 256;
    const int NP0 = 128 * 24 * 512;
    const int NP1 = 128 * 32 * 512;
    for (int e = idx; e < NP0; e += stride) {
        int j = e & 7, l = (e >> 3) & 63, rem = e >> 9;
        int kt = rem % 24, nt = rem / 24;
        int n = nt * 16 + (l & 15);
        int k = kt * 32 + ((l >> 4) << 3) + j;
        float v = (k < HI) ? Wih0[n * HI + k] : Whh0[n * HH + (k - HI)];
        wp0[e] = f2bf(v);
    }
    for (int e = idx; e < NP1; e += stride) {
        int j = e & 7, l = (e >> 3) & 63, rem = e >> 9;
        int kt = rem & 31, nt = rem >> 5;
        int n = nt * 16 + (l & 15);
        int k = kt * 32 + ((l >> 4) << 3) + j;
        float v = (k < HH) ? Wih1[n * HH + k] : Whh1[n * HH + (k - HH)];
        wp1[e] = f2bf(v);
    }
    for (int e = idx; e < 2048; e += stride) {
        bs[e]        = bih0[e] + bhh0[e];
        bs[2048 + e] = bih1[e] + bhh1[e];
    }
}

// ---------------------------------------------------------------------------
// Pack x (B,1,I,T) -> bf16 A-fragment layout xp[t][mt(4)][kt(8)][lane(64)][j(8)]
// ---------------------------------------------------------------------------
__global__ void pack_x(const float* __restrict__ x, unsigned short* __restrict__ xp) {
    int tt = blockIdx.x;   // 64
    int ii = blockIdx.y;   // 8
    int bt = blockIdx.z;   // 4
    int w  = threadIdx.x;  // 256
    __shared__ unsigned short tile[512][16];
    int tloc = w & 15;
    for (int q = 0; q < 32; ++q) {
        int p = q * 16 + (w >> 4);
        int m = p >> 5, iloc = p & 31;
        int b = bt * 16 + m, i = ii * 32 + iloc, t = tt * 16 + tloc;
        tile[p][tloc] = f2bf(x[((size_t)b * HI + i) * HT + t]);
    }
    __syncthreads();
    int e  = w * 2;
    int l  = e >> 3, j0 = e & 7;
    int m  = l & 15;
    int i0 = ((l >> 4) << 3) + j0;
    for (int ti = 0; ti < 16; ++ti) {
        int t = tt * 16 + ti;
        size_t base = ((size_t)(t * 4 + bt) * 8 + ii) * 512;
        unsigned v0 = tile[m * 32 + i0][ti];
        unsigned v1 = tile[m * 32 + i0 + 1][ti];
        ((unsigned int*)xp)[(base + e) >> 1] = v0 | (v1 << 16);
    }
}

// Re-run every launch (graph-captured): zero flag1, sentinel all ring tags.
// Plain stores are fine: kernel-end writeback makes them visible to the
// sc0/sc1-bypass reads of lstm_persist (proven by the round-0 flag scheme).
__global__ void init_sync(int* __restrict__ flag1,
                          int4* __restrict__ h0r, int4* __restrict__ h1r) {
    int idx = blockIdx.x * 256 + threadIdx.x;
    int stride = gridDim.x * 256;
    for (int e = idx; e < 32768; e += stride) flag1[e] = 0;
    int4 s; s.x = 0; s.y = 0; s.z = -1; s.w = -1;
    for (int e = idx; e < 32768; e += stride) h0r[e] = s;   // 4 slots x 128KB
    for (int e = idx; e < 16384; e += stride) h1r[e] = s;   // 2 slots x 128KB
}

// ---------------------------------------------------------------------------
// Persistent pipelined LSTM — tag-fused rings, drain-free, (mostly)
// barrier-free. 64 blocks x 256 threads, 1 block/CU.
// Blocks 0..31: layer0.  Blocks 32..63: layer1.
// h exchange: each 8B of h is stored WITH its step tag as one 16B
// transaction (st_pair16). Consumers pull+validate tags (pull16) — the pull
// IS the readiness poll. Removes per-step: vmcnt(0) drain, flag0 array,
// flag-poll round trip, and all layer0 barriers (stage/ring regions are
// wave-private; waves drift freely).
// Remaining sync: flag1[t] (per-block) = "layer1 block done reading h0(t)",
// used only as layer0's depth-4 anti-dependence gate (off critical path,
// early-issued load). Layer1 keeps ONE barrier/step before setting flag1.
// Slot-reuse safety: h0 dist-4 vs layer1 readers = flag1 gate; vs layer0
// readers = self-sync (reaching t proves peers stored t-1, hence completed
// their t-3 pull of tag t-4). h1 dist-2 = self-sync at distance 2.
// ---------------------------------------------------------------------------
__global__ void __launch_bounds__(256, 1) lstm_persist(
        const unsigned short* __restrict__ wp0,
        const unsigned short* __restrict__ wp1,
        const float* __restrict__ bs,
        const unsigned short* __restrict__ xp,
        char* __restrict__ h0ring,   // 4 slots x [mt4][kt16][lane64][pair2] x 16B
        char* __restrict__ h1ring,   // 2 slots x same
        int* __restrict__ flag1,
        float* __restrict__ out) {
    __shared__ int4 ldsw[8192];                 // 128 KB weight slice
    __shared__ unsigned long long stage[256];   // 2 KB h staging (wave-private)

    const int bid   = blockIdx.x;
    const int layer = bid >> 5;
    const int ut    = bid & 31;
    const int tid   = threadIdx.x;
    const int mt    = tid >> 6;
    const int l     = tid & 63;
    const int ul    = l & 15;
    const int q     = l >> 4;
    const int KT    = layer ? 32 : 24;

    const short8* ldsf = (const short8*)ldsw;
    unsigned short* stage_s = (unsigned short*)stage;

    // ---- stage weight slice into LDS ----
    {
        const unsigned short* wsrc = layer ? wp1 : wp0;
        for (int g = 0; g < 4; ++g) {
            const int4* src = (const int4*)(wsrc + (size_t)(g * 32 + ut) * KT * 512);
            int4* dst = ldsw + (size_t)g * KT * 64;
            for (int i = tid; i < KT * 64; i += 256) dst[i] = src[i];
        }
    }
    float bv[4];
    #pragma unroll
    for (int g = 0; g < 4; ++g) bv[g] = bs[layer * 2048 + g * HH + ut * 16 + ul];
    float cc[4] = {0.f, 0.f, 0.f, 0.f};
    __syncthreads();   // weights ready; the ONLY barrier layer0 ever takes

    const int u = ut * 16 + ul;
    const int stg_w = mt * 256 + (ul >> 3) * 128 + (ul & 7);  // + m*8 at use
    const int ring_sub = (ut >> 1) * 128 + ((2 * ut) & 3) * 32 + (tid & 63);

    for (int t = 0; t < HT; ++t) {
        f32x4 acc[4];
        #pragma unroll
        for (int g = 0; g < 4; ++g) {
            f32x4 a; a[0] = bv[g]; a[1] = bv[g]; a[2] = bv[g]; a[3] = bv[g];
            acc[g] = a;
        }

        if (layer == 0) {
            // Early-issue the anti-dep flag read; checked just before the
            // ring store (overlaps the whole step's compute).
            int fv = 1;
            if (t >= 4 && l < 32)
                fv = __hip_atomic_load(flag1 + (size_t)(t - 4) * 32 + l,
                                       __ATOMIC_RELAXED, __HIP_MEMORY_SCOPE_AGENT);

            // x part: no dependency
            const short8* xa = (const short8*)xp + ((size_t)t * 4 + mt) * 8 * 64;
            #pragma unroll
            for (int kt = 0; kt < 8; ++kt) {
                short8 a = xa[kt * 64 + l];
                #pragma unroll
                for (int g = 0; g < 4; ++g)
                    acc[g] = __builtin_amdgcn_mfma_f32_16x16x32_bf16(
                        a, ldsf[(g * 24 + kt) * 64 + l], acc[g], 0, 0, 0);
            }
            if (t > 0) {
                const char* hb = h0ring +
                    (size_t)((((t - 1) & 3) * 4 + mt)) * 32768 + (size_t)l * 32;
                short8 af[16];
                pull16(hb, t - 1, af);
                #pragma unroll
                for (int kt = 0; kt < 16; ++kt) {
                    #pragma unroll
                    for (int g = 0; g < 4; ++g)
                        acc[g] = __builtin_amdgcn_mfma_f32_16x16x32_bf16(
                            af[kt], ldsf[(g * 24 + 8 + kt) * 64 + l], acc[g], 0, 0, 0);
                }
            }

            // ---- epilogue: activations, cell update, stage h (wave-private) ----
            #pragma unroll
            for (int r = 0; r < 4; ++r) {
                int m = q * 4 + r;
                int b = mt * 16 + m;
                float iv = fsigmoid(acc[0][r]);
                float fv2 = fsigmoid(acc[1][r]);
                float gv = ftanh(acc[2][r]);
                float ov = fsigmoid(acc[3][r]);
                float c = fv2 * cc[r] + iv * gv;
                cc[r] = c;
                float h = ov * ftanh(c);
                stage_s[stg_w + m * 8] = f2bf(h);
                if (t == HT - 1) {
                    out[33554432 + b * 512 + u] = h;   // hidden, layer0
                    out[33619968 + b * 512 + u] = c;   // cell, layer0
                }
            }

            // anti-dep gate: layer1 must be done reading h0(t-4) (slot reuse)
            if (t >= 4) {
                if (__ballot(fv != 0) != ~0ull) {
                    const int* p = flag1 + (size_t)(t - 4) * 32 + (l & 31);
                    while (__ballot((l >= 32) ||
                           (__hip_atomic_load(p, __ATOMIC_RELAXED,
                                              __HIP_MEMORY_SCOPE_AGENT) != 0)) != ~0ull)
                        __builtin_amdgcn_s_sleep(1);
                }
            }

            // tagged ring store: ONE 16B transaction per thread, no drain
            {
                unsigned long long v = stage[tid];
                i32x4 pv;
                pv[0] = (int)(unsigned)(v & 0xffffffffull);
                pv[1] = (int)(unsigned)(v >> 32);
                pv[2] = t; pv[3] = 0;
                char* dst = h0ring +
                    ((size_t)((t & 3) * 4 + mt) * 2048 + ring_sub) * 16;
                st_pair16(dst, pv);
            }
        } else {
            // recurrent half first (bit-identical accumulation order)
            if (t > 0) {
                const char* hb1 = h1ring +
                    (size_t)((((t - 1) & 1) * 4 + mt)) * 32768 + (size_t)l * 32;
                short8 af1[16];
                pull16(hb1, t - 1, af1);
                #pragma unroll
                for (int kt = 0; kt < 16; ++kt) {
                    #pragma unroll
                    for (int g = 0; g < 4; ++g)
                        acc[g] = __builtin_amdgcn_mfma_f32_16x16x32_bf16(
                            af1[kt], ldsf[(g * 32 + 16 + kt) * 64 + l], acc[g], 0, 0, 0);
                }
            }
            // input half: pull h0(t), tag t
            {
                const char* hb0 = h0ring +
                    (size_t)(((t & 3) * 4 + mt)) * 32768 + (size_t)l * 32;
                short8 af0[16];
                pull16(hb0, t, af0);
                #pragma unroll
                for (int kt = 0; kt < 16; ++kt) {
                    #pragma unroll
                    for (int g = 0; g < 4; ++g)
                        acc[g] = __builtin_amdgcn_mfma_f32_16x16x32_bf16(
                            af0[kt], ldsf[(g * 32 + kt) * 64 + l], acc[g], 0, 0, 0);
                }
            }

            // ---- epilogue ----
            #pragma unroll
            for (int r = 0; r < 4; ++r) {
                int m = q * 4 + r;
                int b = mt * 16 + m;
                float iv = fsigmoid(acc[0][r]);
                float fv2 = fsigmoid(acc[1][r]);
                float gv = ftanh(acc[2][r]);
                float ov = fsigmoid(acc[3][r]);
                float c = fv2 * cc[r] + iv * gv;
                cc[r] = c;
                float h = ov * ftanh(c);
                stage_s[stg_w + m * 8] = f2bf(h);
                if (t == HT - 1) {
                    out[33554432 + 32768 + b * 512 + u] = h;   // hidden, layer1
                    out[33619968 + 32768 + b * 512 + u] = c;   // cell, layer1
                }
            }

            // tagged h1 ring store (no drain needed)
            {
                unsigned long long v = stage[tid];
                i32x4 pv;
                pv[0] = (int)(unsigned)(v & 0xffffffffull);
                pv[1] = (int)(unsigned)(v >> 32);
                pv[2] = t; pv[3] = 0;
                char* dst = h1ring +
                    ((size_t)((t & 1) * 4 + mt) * 2048 + ring_sub) * 16;
                st_pair16(dst, pv);
            }

            // publish "h0(t) consumed by ALL 4 waves" for layer0's gate
            __syncthreads();
            if (tid == 0)
                __hip_atomic_store(flag1 + (size_t)t * 32 + ut, 1,
                                   __ATOMIC_RELAXED, __HIP_MEMORY_SCOPE_AGENT);

            // sequence output from stage (own-wave region, cached stores)
            {
                int b = tid >> 2, ch = tid & 3;
                const unsigned short* sp = stage_s + (b >> 4) * 256 + (ch >> 1) * 128 +
                                           (b & 15) * 8 + (ch & 1) * 4;
                f32x4 o;
                o[0] = bf2f(sp[0]); o[1] = bf2f(sp[1]);
                o[2] = bf2f(sp[2]); o[3] = bf2f(sp[3]);
                *(f32x4*)&out[((size_t)b * HT + t) * HH + ut * 16 + ch * 4] = o;
            }
        }
    }
}

extern "C" void kernel_launch(void* const* d_in, const int* in_sizes, int n_in,
                              void* d_out, int out_size, void* d_ws, size_t ws_size,
                              hipStream_t stream) {
    const float* x    = (const float*)d_in[0];
    const float* Wih0 = (const float*)d_in[1];
    const float* Whh0 = (const float*)d_in[2];
    const float* bih0 = (const float*)d_in[3];
    const float* bhh0 = (const float*)d_in[4];
    const float* Wih1 = (const float*)d_in[5];
    const float* Whh1 = (const float*)d_in[6];
    const float* bih1 = (const float*)d_in[7];
    const float* bhh1 = (const float*)d_in[8];

    char* ws = (char*)d_ws;
    // ws layout (bytes) — total 41,828,352, identical to the proven round-0 cap:
    //   wp0:    0          .. 3,145,728
    //   wp1:    3,145,728  .. 7,340,032
    //   bs:     7,340,032  .. 7,356,416
    //   xp:     7,356,416  .. 40,910,848
    //   flag1:  40,910,848 .. 41,041,920   (1024*32 int)
    //   h0ring: 41,041,920 .. 41,566,208   (4 slots x 128 KB tagged pairs)
    //   h1ring: 41,566,208 .. 41,828,352   (2 slots x 128 KB tagged pairs)
    unsigned short* wp0 = (unsigned short*)(ws + 0);
    unsigned short* wp1 = (unsigned short*)(ws + 3145728);
    float*          bsv = (float*)(ws + 7340032);
    unsigned short* xp  = (unsigned short*)(ws + 7356416);
    int*   flag1        = (int*)(ws + 40910848);
    char*  h0r          = (char*)(ws + 41041920);
    char*  h1r          = (char*)(ws + 41566208);
    float* out = (float*)d_out;

    pack_weights<<<2048, 256, 0, stream>>>(Wih0, Whh0, bih0, bhh0,
                                           Wih1, Whh1, bih1, bhh1, wp0, wp1, bsv);
    pack_x<<<dim3(64, 8, 4), 256, 0, stream>>>(x, xp);
    init_sync<<<64, 256, 0, stream>>>(flag1, (int4*)h0r, (int4*)h1r);

    lstm_persist<<<64, 256, 0, stream>>>(wp0, wp1, bsv, xp, h0r, h1r,
                                         flag1, out);
}

// Round 5
// 7487.310 us; speedup vs baseline: 1.6550x; 1.6550x over previous
//
#include <hip/hip_runtime.h>

#define HB 64      // batch
#define HT 1024    // time
#define HI 256     // input dim
#define HH 512     // hidden dim

typedef short short8 __attribute__((ext_vector_type(8)));
typedef float f32x4 __attribute__((ext_vector_type(4)));
typedef int   i32x4 __attribute__((ext_vector_type(4)));   // asm-friendly 16B

__device__ __forceinline__ unsigned short f2bf(float f) {
    unsigned u = __float_as_uint(f);
    u += 0x7FFF + ((u >> 16) & 1);          // round-to-nearest-even
    return (unsigned short)(u >> 16);
}
__device__ __forceinline__ float bf2f(unsigned short s) {
    return __uint_as_float(((unsigned)s) << 16);
}
__device__ __forceinline__ float fsigmoid(float x) {
    return __builtin_amdgcn_rcpf(1.0f + __expf(-x));
}
__device__ __forceinline__ float ftanh(float x) {
    return 1.0f - 2.0f * __builtin_amdgcn_rcpf(__expf(2.0f * x) + 1.0f);
}

// 16B coherence-point store: {8B data, 4B tag, 4B zero} in ONE transaction.
__device__ __forceinline__ void st_pair16(void* p, i32x4 v) {
    asm volatile("global_store_dwordx4 %0, %1, off sc0 sc1"
                 :: "v"(p), "v"(v) : "memory");
}

// Same-wave LDS ordering fence (writes visible to later reads, compiler
// barred from reordering around it).
__device__ __forceinline__ void lds_fence() {
    asm volatile("s_waitcnt lgkmcnt(0)" ::: "memory");
    __builtin_amdgcn_sched_barrier(0);
}

// ---------------------------------------------------------------------------
// Tag-validated h pull for ONE wave's mt region: 16 fragments = 32 tagged
// 16B pairs per lane. Steady state: flags (or producer lookahead) guarantee
// tags valid -> exactly one attempt. Retry is the rare-reorder safety net.
// FUEL WATCHDOG: on exhaustion, accept current data and proceed — converts
// any protocol bug into a visible wrong-answer failure instead of a wedged
// container. Never triggers when the protocol is live (fuel >= 40x any
// legitimate transient). Zero cost on the first-attempt-success path.
// Layout per (slot,mt): kt(16) x lane(64) x pair(2) x 16B.
// ---------------------------------------------------------------------------
__device__ __forceinline__ void pull16(const char* base0, int expect, short8* af,
                                       int& fuel) {
    for (;;) {
        i32x4 v[32];
        const char* b = base0;
        #pragma unroll
        for (int bi = 0; bi < 8; ++bi) {   // 2 kt per bi
            asm volatile("global_load_dwordx4 %0, %1, off sc0 sc1"
                         : "=v"(v[bi * 4 + 0]) : "v"(b));
            asm volatile("global_load_dwordx4 %0, %1, off offset:16 sc0 sc1"
                         : "=v"(v[bi * 4 + 1]) : "v"(b));
            asm volatile("global_load_dwordx4 %0, %1, off offset:2048 sc0 sc1"
                         : "=v"(v[bi * 4 + 2]) : "v"(b));
            asm volatile("global_load_dwordx4 %0, %1, off offset:2064 sc0 sc1"
                         : "=v"(v[bi * 4 + 3]) : "v"(b));
            b += 4096;
        }
        asm volatile("s_waitcnt vmcnt(0)" ::: "memory");
        __builtin_amdgcn_sched_barrier(0);   // keep tag checks after the wait
        int ok = 1;
        #pragma unroll
        for (int i = 0; i < 32; ++i)
            ok &= (v[i][2] == expect) & (v[i][3] == 0);
        bool done = (__ballot(ok != 0) == ~0ull);
        if (!done) {
            fuel -= 64;                      // heavy retry: 64 fuel units
            if (fuel > 0) { __builtin_amdgcn_s_sleep(2); continue; }
        }
        #pragma unroll
        for (int kt = 0; kt < 16; ++kt) {
            union { int i4[4]; short8 s; } u;
            u.i4[0] = v[2 * kt][0];     u.i4[1] = v[2 * kt][1];
            u.i4[2] = v[2 * kt + 1][0]; u.i4[3] = v[2 * kt + 1][1];
            af[kt] = u.s;
        }
        return;
    }
}

// ---------------------------------------------------------------------------
// Pack weights to bf16 in MFMA B-fragment-linear layout (proven round 1).
// ---------------------------------------------------------------------------
__global__ void pack_weights(const float* __restrict__ Wih0, const float* __restrict__ Whh0,
                             const float* __restrict__ bih0, const float* __restrict__ bhh0,
                             const float* __restrict__ Wih1, const float* __restrict__ Whh1,
                             const float* __restrict__ bih1, const float* __restrict__ bhh1,
                             unsigned short* __restrict__ wp0,
                             unsigned short* __restrict__ wp1,
                             float* __restrict__ bs) {
    int idx = blockIdx.x * 256 + threadIdx.x;
    int stride = gridDim.x * 256;
    const int NP0 = 128 * 24 * 512;
    const int NP1 = 128 * 32 * 512;
    for (int e = idx; e < NP0; e += stride) {
        int j = e & 7, l = (e >> 3) & 63, rem = e >> 9;
        int kt = rem % 24, nt = rem / 24;
        int n = nt * 16 + (l & 15);
        int k = kt * 32 + ((l >> 4) << 3) + j;
        float v = (k < HI) ? Wih0[n * HI + k] : Whh0[n * HH + (k - HI)];
        wp0[e] = f2bf(v);
    }
    for (int e = idx; e < NP1; e += stride) {
        int j = e & 7, l = (e >> 3) & 63, rem = e >> 9;
        int kt = rem & 31, nt = rem >> 5;
        int n = nt * 16 + (l & 15);
        int k = kt * 32 + ((l >> 4) << 3) + j;
        float v = (k < HH) ? Wih1[n * HH + k] : Whh1[n * HH + (k - HH)];
        wp1[e] = f2bf(v);
    }
    for (int e = idx; e < 2048; e += stride) {
        bs[e]        = bih0[e] + bhh0[e];
        bs[2048 + e] = bih1[e] + bhh1[e];
    }
}

// ---------------------------------------------------------------------------
// Pack x (B,1,I,T) -> bf16 A-fragment layout xp[t][mt(4)][kt(8)][lane(64)][j(8)]
// ---------------------------------------------------------------------------
__global__ void pack_x(const float* __restrict__ x, unsigned short* __restrict__ xp) {
    int tt = blockIdx.x;   // 64
    int ii = blockIdx.y;   // 8
    int bt = blockIdx.z;   // 4
    int w  = threadIdx.x;  // 256
    __shared__ unsigned short tile[512][16];
    int tloc = w & 15;
    for (int q = 0; q < 32; ++q) {
        int p = q * 16 + (w >> 4);
        int m = p >> 5, iloc = p & 31;
        int b = bt * 16 + m, i = ii * 32 + iloc, t = tt * 16 + tloc;
        tile[p][tloc] = f2bf(x[((size_t)b * HI + i) * HT + t]);
    }
    __syncthreads();
    int e  = w * 2;
    int l  = e >> 3, j0 = e & 7;
    int m  = l & 15;
    int i0 = ((l >> 4) << 3) + j0;
    for (int ti = 0; ti < 16; ++ti) {
        int t = tt * 16 + ti;
        size_t base = ((size_t)(t * 4 + bt) * 8 + ii) * 512;
        unsigned v0 = tile[m * 32 + i0][ti];
        unsigned v1 = tile[m * 32 + i0 + 1][ti];
        ((unsigned int*)xp)[(base + e) >> 1] = v0 | (v1 << 16);
    }
}

// Re-run every launch (graph-captured): zero the 256 monotonic step-counters,
// sentinel all ring tags (stale tags from a previous launch would alias).
// Plain stores are visible to the sc0/sc1 reads of lstm_persist across the
// dispatch boundary (empirically proven: round-3 passed bit-exact over ~70
// graph replays with this exact init pattern).
__global__ void init_sync(int* __restrict__ flags,
                          int4* __restrict__ h0r, int4* __restrict__ h1r) {
    int idx = blockIdx.x * 256 + threadIdx.x;
    int stride = gridDim.x * 256;
    for (int e = idx; e < 256; e += stride) flags[e] = 0;
    int4 s; s.x = 0; s.y = 0; s.z = -1; s.w = -1;
    for (int e = idx; e < 32768; e += stride) h0r[e] = s;   // 4 slots x 128KB
    for (int e = idx; e < 16384; e += stride) h1r[e] = s;   // 2 slots x 128KB
}

// ---------------------------------------------------------------------------
// Persistent pipelined LSTM — per-WAVE decoupled, barrier-free step loop.
// 64 blocks x 256 threads, 1 block/CU. Blocks 0..31: layer0; 32..63: layer1.
// KEY: batch tiles (mt = wave id) are independent recurrences. Each wave
// syncs only with same-mt waves of other blocks:
//   - flags = 128 ints/layer, flagX[mt*32+ut] = (last finished step)+1,
//     monotonic, same hot cachelines every step (no per-t arrays).
//   - h rings carry {8B data, 4B step tag} 16B pairs (round-3-proven);
//     flags published immediately after ring stores (NO pre-flag drain —
//     tags catch the flag-beats-data window with a one-shot cheap retry).
//   - layer1's h0 feed is TAG-ONLY: layer0 runs 3-4 steps ahead against the
//     depth-4 ring gate, so tags are valid on first pull (no discovery RT).
//   - post-flag vmcnt(0) keeps the vmem queue clean for the next poll but
//     sits OFF the inter-block chain (flag already departed).
//   - NO __syncthreads in the loop; LDS stage is wave-private (lds_fence).
//   - FUEL WATCHDOG per wave: any protocol stall degrades to a visible
//     wrong-answer failure (absmax canary) instead of a wedged device.
// Slot-reuse safety: h0 dist-4 vs layer1 = flag1 >= t-3 gate; vs layer0
// peers = self-sync (flag0 >= t proves peers finished t-1 > their t-3 pull
// of tag t-4). h1 dist-2 = self-sync via flag1 >= t. MFMA accumulation
// order identical to round-0 -> absmax must be bit-identical (race canary).
// Liveness induction: all waves completing <=t-1 implies layer0 completes t
// (needs flag0>=t, flag1>=t-3) then layer1 completes t (tags t appear).
// ---------------------------------------------------------------------------
__global__ void __launch_bounds__(256, 1) lstm_persist(
        const unsigned short* __restrict__ wp0,
        const unsigned short* __restrict__ wp1,
        const float* __restrict__ bs,
        const unsigned short* __restrict__ xp,
        char* __restrict__ h0ring,   // 4 slots x [mt4][kt16][lane64][pair2] x 16B
        char* __restrict__ h1ring,   // 2 slots x same
        int* __restrict__ flag0,     // [mt4][ut32] monotonic step+1
        int* __restrict__ flag1,     // [mt4][ut32] monotonic step+1
        float* __restrict__ out) {
    __shared__ int4 ldsw[8192];                    // 128 KB weight slice
    __shared__ unsigned short stage_s[1024];       // 2 KB h staging (wave-private)

    const int bid   = blockIdx.x;
    const int layer = bid >> 5;
    const int ut    = bid & 31;
    const int tid   = threadIdx.x;
    const int mt    = tid >> 6;
    const int l     = tid & 63;
    const int ul    = l & 15;
    const int q     = l >> 4;
    const int KT    = layer ? 32 : 24;

    const short8* ldsf = (const short8*)ldsw;

    // ---- stage weight slice into LDS ----
    {
        const unsigned short* wsrc = layer ? wp1 : wp0;
        for (int g = 0; g < 4; ++g) {
            const int4* src = (const int4*)(wsrc + (size_t)(g * 32 + ut) * KT * 512);
            int4* dst = ldsw + (size_t)g * KT * 64;
            for (int i = tid; i < KT * 64; i += 256) dst[i] = src[i];
        }
    }
    float bv[4];
    #pragma unroll
    for (int g = 0; g < 4; ++g) bv[g] = bs[layer * 2048 + g * HH + ut * 16 + ul];
    float cc[4] = {0.f, 0.f, 0.f, 0.f};
    __syncthreads();   // weights ready; the ONLY barrier in the kernel

    const int u = ut * 16 + ul;
    const int stg_w = mt * 256 + (ul >> 3) * 128 + (ul & 7);  // + m*8 at use
    const int ring_sub = (ut >> 1) * 128 + ((2 * ut) & 3) * 32 + l;

    // per-wave poll pointers (hot, same cacheline every step)
    const int* pp0 = (l < 32) ? (flag0 + mt * 32 + l)          // layer0: peer flag0
                              : (flag1 + mt * 32 + (l - 32));  // layer0: anti-dep
    const int* pp1 = flag1 + mt * 32 + (l & 31);               // layer1: peer flag1

    // watchdog fuel: ~8.4M light spins total per wave; legit usage << 1M.
    int fuel = 1 << 23;

    for (int t = 0; t < HT; ++t) {
        f32x4 acc[4];
        #pragma unroll
        for (int g = 0; g < 4; ++g) {
            f32x4 a; a[0] = bv[g]; a[1] = bv[g]; a[2] = bv[g]; a[3] = bv[g];
            acc[g] = a;
        }

        if (layer == 0) {
            // early-issue combined poll: lanes 0-31 peer flag0 (need >= t),
            // lanes 32-63 anti-dep flag1 (need >= t-3, active from t>=4).
            const bool act  = (l < 32) ? (t > 0) : (t >= 4);
            const int  need = (l < 32) ? t : (t - 3);
            int pf = act ? __hip_atomic_load(pp0, __ATOMIC_RELAXED,
                                             __HIP_MEMORY_SCOPE_AGENT)
                         : 0x7fffffff;

            // x part: no dependency, overlaps flag latency
            const short8* xa = (const short8*)xp + ((size_t)t * 4 + mt) * 8 * 64;
            #pragma unroll
            for (int kt = 0; kt < 8; ++kt) {
                short8 a = xa[kt * 64 + l];
                #pragma unroll
                for (int g = 0; g < 4; ++g)
                    acc[g] = __builtin_amdgcn_mfma_f32_16x16x32_bf16(
                        a, ldsf[(g * 24 + kt) * 64 + l], acc[g], 0, 0, 0);
            }
            if (t > 0) {
                for (;;) {
                    if (__ballot(pf >= need) == ~0ull) break;
                    if (--fuel <= 0) break;            // watchdog
                    __builtin_amdgcn_s_sleep(1);
                    if (act) pf = __hip_atomic_load(pp0, __ATOMIC_RELAXED,
                                                    __HIP_MEMORY_SCOPE_AGENT);
                }
                const char* hb = h0ring +
                    (size_t)((((t - 1) & 3) * 4 + mt)) * 32768 + (size_t)l * 32;
                short8 af[16];
                pull16(hb, t - 1, af, fuel);
                #pragma unroll
                for (int kt = 0; kt < 16; ++kt) {
                    #pragma unroll
                    for (int g = 0; g < 4; ++g)
                        acc[g] = __builtin_amdgcn_mfma_f32_16x16x32_bf16(
                            af[kt], ldsf[(g * 24 + 8 + kt) * 64 + l], acc[g], 0, 0, 0);
                }
            }

            // ---- epilogue: activations, cell update, stage h (wave-private) ----
            #pragma unroll
            for (int r = 0; r < 4; ++r) {
                int m = q * 4 + r;
                int b = mt * 16 + m;
                float iv = fsigmoid(acc[0][r]);
                float fv2 = fsigmoid(acc[1][r]);
                float gv = ftanh(acc[2][r]);
                float ov = fsigmoid(acc[3][r]);
                float c = fv2 * cc[r] + iv * gv;
                cc[r] = c;
                float h = ov * ftanh(c);
                stage_s[stg_w + m * 8] = f2bf(h);
                if (t == HT - 1) {
                    out[33554432 + b * 512 + u] = h;   // hidden, layer0
                    out[33619968 + b * 512 + u] = c;   // cell, layer0
                }
            }
            lds_fence();   // same-wave stage writes -> reads

            // tagged ring store (no drain before flag; tags cover reorder)
            {
                unsigned s0 = stage_s[tid * 4 + 0], s1 = stage_s[tid * 4 + 1];
                unsigned s2 = stage_s[tid * 4 + 2], s3 = stage_s[tid * 4 + 3];
                i32x4 pv;
                pv[0] = (int)(s0 | (s1 << 16));
                pv[1] = (int)(s2 | (s3 << 16));
                pv[2] = t; pv[3] = 0;
                char* dst = h0ring +
                    ((size_t)((t & 3) * 4 + mt) * 2048 + ring_sub) * 16;
                st_pair16(dst, pv);
            }
            if (l == 0)
                __hip_atomic_store(flag0 + mt * 32 + ut, t + 1,
                                   __ATOMIC_RELAXED, __HIP_MEMORY_SCOPE_AGENT);
            // clean the vmem queue so next step's polls don't drain stores
            asm volatile("s_waitcnt vmcnt(0)" ::: "memory");
        } else {
            // early-issue peer flag1 poll (lanes 0-31; need >= t)
            int pf = (t > 0 && l < 32)
                         ? __hip_atomic_load(pp1, __ATOMIC_RELAXED,
                                             __HIP_MEMORY_SCOPE_AGENT)
                         : 0x7fffffff;

            if (t > 0) {
                for (;;) {
                    if (__ballot(pf >= t) == ~0ull) break;
                    if (--fuel <= 0) break;            // watchdog
                    __builtin_amdgcn_s_sleep(1);
                    if (l < 32) pf = __hip_atomic_load(pp1, __ATOMIC_RELAXED,
                                                       __HIP_MEMORY_SCOPE_AGENT);
                }
                const char* hb1 = h1ring +
                    (size_t)((((t - 1) & 1) * 4 + mt)) * 32768 + (size_t)l * 32;
                short8 af1[16];
                pull16(hb1, t - 1, af1, fuel);
                #pragma unroll
                for (int kt = 0; kt < 16; ++kt) {
                    #pragma unroll
                    for (int g = 0; g < 4; ++g)
                        acc[g] = __builtin_amdgcn_mfma_f32_16x16x32_bf16(
                            af1[kt], ldsf[(g * 32 + 16 + kt) * 64 + l], acc[g], 0, 0, 0);
                }
            }
            // input half: TAG-ONLY pull of h0(t) — layer0 runs ahead, so
            // first attempt validates; no flag discovery RT.
            {
                const char* hb0 = h0ring +
                    (size_t)(((t & 3) * 4 + mt)) * 32768 + (size_t)l * 32;
                short8 af0[16];
                pull16(hb0, t, af0, fuel);
                #pragma unroll
                for (int kt = 0; kt < 16; ++kt) {
                    #pragma unroll
                    for (int g = 0; g < 4; ++g)
                        acc[g] = __builtin_amdgcn_mfma_f32_16x16x32_bf16(
                            af0[kt], ldsf[(g * 32 + kt) * 64 + l], acc[g], 0, 0, 0);
                }
            }

            // ---- epilogue ----
            #pragma unroll
            for (int r = 0; r < 4; ++r) {
                int m = q * 4 + r;
                int b = mt * 16 + m;
                float iv = fsigmoid(acc[0][r]);
                float fv2 = fsigmoid(acc[1][r]);
                float gv = ftanh(acc[2][r]);
                float ov = fsigmoid(acc[3][r]);
                float c = fv2 * cc[r] + iv * gv;
                cc[r] = c;
                float h = ov * ftanh(c);
                stage_s[stg_w + m * 8] = f2bf(h);
                if (t == HT - 1) {
                    out[33554432 + 32768 + b * 512 + u] = h;   // hidden, layer1
                    out[33619968 + 32768 + b * 512 + u] = c;   // cell, layer1
                }
            }
            lds_fence();   // same-wave stage writes -> reads

            // tagged h1 ring store; flag1 right after (certifies h1(t) stored
            // AND h0(t) consumed -> also layer0's anti-dep signal)
            {
                unsigned s0 = stage_s[tid * 4 + 0], s1 = stage_s[tid * 4 + 1];
                unsigned s2 = stage_s[tid * 4 + 2], s3 = stage_s[tid * 4 + 3];
                i32x4 pv;
                pv[0] = (int)(s0 | (s1 << 16));
                pv[1] = (int)(s2 | (s3 << 16));
                pv[2] = t; pv[3] = 0;
                char* dst = h1ring +
                    ((size_t)((t & 1) * 4 + mt) * 2048 + ring_sub) * 16;
                st_pair16(dst, pv);
            }
            if (l == 0)
                __hip_atomic_store(flag1 + mt * 32 + ut, t + 1,
                                   __ATOMIC_RELAXED, __HIP_MEMORY_SCOPE_AGENT);

            // sequence output from OWN wave's stage region (cached stores),
            // issued after the flag, covered by the drain below.
            {
                int lb = l >> 2, ch = l & 3;
                int b = mt * 16 + lb;
                const unsigned short* sp = stage_s + mt * 256 + (ch >> 1) * 128 +
                                           lb * 8 + (ch & 1) * 4;
                f32x4 o;
                o[0] = bf2f(sp[0]); o[1] = bf2f(sp[1]);
                o[2] = bf2f(sp[2]); o[3] = bf2f(sp[3]);
                *(f32x4*)&out[((size_t)b * HT + t) * HH + ut * 16 + ch * 4] = o;
            }
            // clean the vmem queue so next step's polls don't drain stores
            asm volatile("s_waitcnt vmcnt(0)" ::: "memory");
        }
    }
}

extern "C" void kernel_launch(void* const* d_in, const int* in_sizes, int n_in,
                              void* d_out, int out_size, void* d_ws, size_t ws_size,
                              hipStream_t stream) {
    const float* x    = (const float*)d_in[0];
    const float* Wih0 = (const float*)d_in[1];
    const float* Whh0 = (const float*)d_in[2];
    const float* bih0 = (const float*)d_in[3];
    const float* bhh0 = (const float*)d_in[4];
    const float* Wih1 = (const float*)d_in[5];
    const float* Whh1 = (const float*)d_in[6];
    const float* bih1 = (const float*)d_in[7];
    const float* bhh1 = (const float*)d_in[8];

    char* ws = (char*)d_ws;
    // ws layout (bytes) — total 41,828,352, same cap as proven rounds:
    //   wp0:    0          .. 3,145,728
    //   wp1:    3,145,728  .. 7,340,032
    //   bs:     7,340,032  .. 7,356,416
    //   xp:     7,356,416  .. 40,910,848
    //   flag0:  40,910,848 .. 40,911,360   (128 int, monotonic)
    //   flag1:  40,911,360 .. 40,911,872   (128 int, monotonic)
    //   h0ring: 41,041,920 .. 41,566,208   (4 slots x 128 KB tagged pairs)
    //   h1ring: 41,566,208 .. 41,828,352   (2 slots x 128 KB tagged pairs)
    unsigned short* wp0 = (unsigned short*)(ws + 0);
    unsigned short* wp1 = (unsigned short*)(ws + 3145728);
    float*          bsv = (float*)(ws + 7340032);
    unsigned short* xp  = (unsigned short*)(ws + 7356416);
    int*   flag0        = (int*)(ws + 40910848);
    int*   flag1        = (int*)(ws + 40911360);
    char*  h0r          = (char*)(ws + 41041920);
    char*  h1r          = (char*)(ws + 41566208);
    float* out = (float*)d_out;

    pack_weights<<<2048, 256, 0, stream>>>(Wih0, Whh0, bih0, bhh0,
                                           Wih1, Whh1, bih1, bhh1, wp0, wp1, bsv);
    pack_x<<<dim3(64, 8, 4), 256, 0, stream>>>(x, xp);
    init_sync<<<64, 256, 0, stream>>>(flag0, (int4*)h0r, (int4*)h1r);

    lstm_persist<<<64, 256, 0, stream>>>(wp0, wp1, bsv, xp, h0r, h1r,
                                         flag0, flag1, out);
}